// Round 3
// baseline (54157.874 us; speedup 1.0000x reference)
//
#include <hip/hip_runtime.h>
#include <math.h>

// Problem constants: U=H=1024, B=32, T=256.
#define UU 1024
#define BB 32
#define TT 256
#define KCH 128          // k per staged chunk
#define NCH 8            // chunks per K=1024
#define NJT 256          // j-tiles per cell (j-tile = 4)
#define PACKF 3072       // floats per (jt,kc) packed block: 2048 A4 + 1024 B2

// ---------------------------------------------------------------------------
// Pack weights: Wih/Whh (3U x U, row-major) -> per-(jt,kc) contiguous block:
//   A-region: entry (kr,jc) = float4 {ih_r, ih_z, ih_n, hh_r}, idx = kr*4+jc
//   B-region: entry (kr,jc) = float2 {hh_z, hh_n}
// Block layout byte-linear so stage loads are 3 coalesced float4 per thread.
// ---------------------------------------------------------------------------
__global__ void pack_kernel(const float* __restrict__ Wih,
                            const float* __restrict__ Whh,
                            float* __restrict__ packed) {
    __shared__ float ls[24][136];   // rows: 0-11 Wih g0..2 x jc, 12-23 Whh
    int jt = blockIdx.x >> 3, kc = blockIdx.x & 7;
    int tid = threadIdx.x;
    int l32 = tid & 31;
    for (int it = 0; it < 3; ++it) {
        int row = it * 8 + (tid >> 5);
        int gate = (row < 12) ? (row >> 2) : ((row - 12) >> 2);
        int jc = row & 3;
        const float* W = (row < 12) ? Wih : Whh;
        float4 v = *(const float4*)&W[((size_t)(gate * UU + jt * 4 + jc)) * UU + kc * KCH + l32 * 4];
        *(float4*)&ls[row][l32 * 4] = v;
    }
    __syncthreads();
    float* dst = packed + (size_t)(jt * NCH + kc) * PACKF;
    for (int it = 0; it < 8; ++it) {      // A-region: 2048 floats
        int e = it * 256 + tid;
        int c = e & 3, jc = (e >> 2) & 3, kr = e >> 4;
        dst[e] = (c < 3) ? ls[c * 4 + jc][kr] : ls[12 + jc][kr];
    }
    for (int it = 0; it < 4; ++it) {      // B-region: 1024 floats
        int e = it * 256 + tid;
        int c2 = e & 1, jc = (e >> 1) & 3, kr = e >> 3;
        dst[2048 + e] = ls[16 + c2 * 4 + jc][kr];
    }
}

// ---------------------------------------------------------------------------
// q_all[t][b][u] = sum_k inputs[b][t][k] * global_W[k][u]
// ---------------------------------------------------------------------------
__global__ void qall_kernel(const float* __restrict__ x,
                            const float* __restrict__ gW,
                            float* __restrict__ q) {
    __shared__ float xs[32][65];
    int r0 = blockIdx.x * 32, u0 = blockIdx.y * 32;
    int tid = threadIdx.x;
    int rr = tid >> 3, ju = tid & 7;
    float4 acc = {0.f, 0.f, 0.f, 0.f};
    for (int k0 = 0; k0 < UU; k0 += 64) {
        for (int e = tid; e < 32 * 64; e += 256) {
            int lr = e >> 6, lk = e & 63;
            int r = r0 + lr;
            int tt = r >> 5, bb = r & 31;
            xs[lr][lk] = x[((size_t)bb * TT + tt) * UU + k0 + lk];
        }
        __syncthreads();
        #pragma unroll 4
        for (int kk = 0; kk < 64; ++kk) {
            float4 gv = *(const float4*)&gW[(size_t)(k0 + kk) * UU + u0 + ju * 4];
            float xv = xs[rr][kk];
            acc.x += xv * gv.x; acc.y += xv * gv.y;
            acc.z += xv * gv.z; acc.w += xv * gv.w;
        }
        __syncthreads();
    }
    *(float4*)&q[(size_t)(r0 + rr) * UU + u0 + ju * 4] = acc;
}

// Zero hist row 0, P slots 0/2; prep xg slots for t=0,1 (p_cur = 0).
__global__ void init_kernel(const float* __restrict__ inputs,
                            float* __restrict__ hist,
                            float* __restrict__ P,
                            float* __restrict__ xg) {
    int i = blockIdx.x * 256 + threadIdx.x;  // 0..32767
    int b = i >> 10, u = i & 1023;
    hist[i] = 0.f;
    P[i] = 0.f;
    P[(size_t)2 * BB * UU + i] = 0.f;
    xg[i] = inputs[(size_t)b * TT * UU + u];
    xg[(size_t)BB * UU + i] = inputs[(size_t)b * TT * UU + UU + u];
}

struct AttSm { float sc[132]; float red[8]; float pct[4][UU]; };
union SmU { float wbuf[2][PACKF]; AttSm a; };

// ---------------------------------------------------------------------------
// Fused GRU cell, j-tile 4, all 32 b, 2-way k-split per thread.
// tid = b*8 + jj*2 + kp.  Double-buffered weight staging (regs->LDS).
// COMBINE: x[b][k] = xU[b*T*U+k] + a1*c1[b*U+k] + a2*c2[b*U+k], else xA[b*U+k].
// ---------------------------------------------------------------------------
template<bool COMBINE>
__device__ __forceinline__ void gru4(
    float (*wb)[PACKF], int tid, int jt,
    const float* __restrict__ pack,
    const float* __restrict__ xA,
    const float* __restrict__ xU, float a1, const float* __restrict__ c1,
    float a2, const float* __restrict__ c2,
    const float* __restrict__ hIn, size_t hStr,
    const float* __restrict__ bih, const float* __restrict__ bhh,
    float* __restrict__ hOut, size_t outStr,
    const float* __restrict__ epiU, float* __restrict__ epiDst) {
    const int b = tid >> 3, jj = (tid >> 1) & 3, kp = tid & 1;
    float air = 0.f, aiz = 0.f, ain = 0.f, ahr = 0.f, ahz = 0.f, ahn = 0.f;
    {   // prologue: stage chunk 0 into wbuf[0]
        const float4* src = (const float4*)(pack + (size_t)jt * NCH * PACKF);
        float4 s0 = src[tid], s1 = src[256 + tid], s2 = src[512 + tid];
        float4* d = (float4*)wb[0];
        d[tid] = s0; d[256 + tid] = s1; d[512 + tid] = s2;
    }
    __syncthreads();
    for (int kc = 0; kc < NCH; ++kc) {
        int cur = kc & 1;
        float4 s0, s1, s2;
        if (kc + 1 < NCH) {   // issue next-chunk loads early (fly during compute)
            const float4* src = (const float4*)(pack + (size_t)(jt * NCH + kc + 1) * PACKF);
            s0 = src[tid]; s1 = src[256 + tid]; s2 = src[512 + tid];
        }
        const float* wA = wb[cur];
        const float* wB = wb[cur] + 2048;
        int kbase = kc * KCH + kp * 64;
        #pragma unroll 4
        for (int kr4 = 0; kr4 < 16; ++kr4) {
            int k = kbase + kr4 * 4;
            float4 xv;
            if (COMBINE) {
                float4 uv = *(const float4*)&xU[(size_t)b * TT * UU + k];
                float4 v1 = *(const float4*)&c1[(size_t)b * UU + k];
                float4 v2 = *(const float4*)&c2[(size_t)b * UU + k];
                xv.x = uv.x + a1 * v1.x + a2 * v2.x;
                xv.y = uv.y + a1 * v1.y + a2 * v2.y;
                xv.z = uv.z + a1 * v1.z + a2 * v2.z;
                xv.w = uv.w + a1 * v1.w + a2 * v2.w;
            } else {
                xv = *(const float4*)&xA[(size_t)b * UU + k];
            }
            float4 hv;
            if (hIn) hv = *(const float4*)&hIn[(size_t)b * hStr + k];
            else hv = {0.f, 0.f, 0.f, 0.f};
            #pragma unroll
            for (int u = 0; u < 4; ++u) {
                int krl = kp * 64 + kr4 * 4 + u;
                float4 wa = *(const float4*)&wA[(size_t)(krl * 4 + jj) * 4];
                float2 wv = *(const float2*)&wB[(size_t)(krl * 4 + jj) * 2];
                float xs = (&xv.x)[u], hs = (&hv.x)[u];
                air += xs * wa.x; aiz += xs * wa.y; ain += xs * wa.z;
                ahr += hs * wa.w; ahz += hs * wv.x; ahn += hs * wv.y;
            }
        }
        if (kc + 1 < NCH) {   // write-late into the other buffer
            float4* d = (float4*)wb[cur ^ 1];
            d[tid] = s0; d[256 + tid] = s1; d[512 + tid] = s2;
        }
        __syncthreads();
    }
    // combine the two k-halves (lanes kp=0/1 are partners)
    air += __shfl_xor(air, 1); aiz += __shfl_xor(aiz, 1); ain += __shfl_xor(ain, 1);
    ahr += __shfl_xor(ahr, 1); ahz += __shfl_xor(ahz, 1); ahn += __shfl_xor(ahn, 1);
    if (kp == 0) {
        int j = jt * 4 + jj;
        float hprev = hIn ? hIn[(size_t)b * hStr + j] : 0.f;
        float r = 1.f / (1.f + expf(-(air + bih[j] + ahr + bhh[j])));
        float z = 1.f / (1.f + expf(-(aiz + bih[UU + j] + ahz + bhh[UU + j])));
        float n = tanhf(ain + bih[2 * UU + j] + r * (ahn + bhh[2 * UU + j]));
        float val = (1.f - z) * n + z * hprev;
        hOut[(size_t)b * outStr + j] = val;
        if (epiDst) epiDst[(size_t)b * UU + j] = epiU[(size_t)b * TT * UU + j] + val;
    }
}

// ---------------------------------------------------------------------------
// Attention half h for batch b at step t: rows [r0,r1) of hist[0..t].
// Writes UNNORMALIZED partials: ctx_h = sum e^{s-m_h} hist, plus (m_h, l_h).
// ---------------------------------------------------------------------------
__device__ __forceinline__ void att_half(
    AttSm* sm, int b, int h, int tid, int t,
    const float* __restrict__ hist,
    const float* __restrict__ qt,       // qall + t*B*U
    float* __restrict__ attC, float* __restrict__ attML) {
    int nt = t + 1;
    int n1 = (nt + 1) >> 1;
    int r0 = h ? n1 : 0;
    int r1 = h ? nt : n1;
    int n = r1 - r0;
    if (n <= 0) {   // empty half: neutral partials
        *(float4*)&attC[(size_t)b * UU + tid * 4] = float4{0.f, 0.f, 0.f, 0.f};
        if (tid == 0) { attML[b * 2] = -INFINITY; attML[b * 2 + 1] = 0.f; }
        return;
    }
    int wave = tid >> 6, lane = tid & 63;
    const float* qb = qt + (size_t)b * UU;
    float4 qr[4];
    #pragma unroll
    for (int m = 0; m < 4; ++m) qr[m] = *(const float4*)&qb[m * 256 + lane * 4];
    for (int tp = r0 + wave; tp < r1; tp += 4) {
        const float* hr = hist + ((size_t)tp * BB + b) * UU;
        float s = 0.f;
        #pragma unroll
        for (int m = 0; m < 4; ++m) {
            float4 hv = *(const float4*)&hr[m * 256 + lane * 4];
            s += hv.x * qr[m].x + hv.y * qr[m].y + hv.z * qr[m].z + hv.w * qr[m].w;
        }
        #pragma unroll
        for (int off = 32; off; off >>= 1) s += __shfl_xor(s, off);
        if (lane == 0) sm->sc[tp - r0] = s;
    }
    __syncthreads();
    float v = (tid < n) ? sm->sc[tid] : -INFINITY;   // n <= 129 <= 256
    float mx = v;
    #pragma unroll
    for (int off = 32; off; off >>= 1) mx = fmaxf(mx, __shfl_xor(mx, off));
    if (lane == 0) sm->red[wave] = mx;
    __syncthreads();
    mx = fmaxf(fmaxf(sm->red[0], sm->red[1]), fmaxf(sm->red[2], sm->red[3]));
    float ev = (tid < n) ? expf(v - mx) : 0.f;
    float sum = ev;
    #pragma unroll
    for (int off = 32; off; off >>= 1) sum += __shfl_xor(sum, off);
    if (lane == 0) sm->red[4 + wave] = sum;
    __syncthreads();
    float l = sm->red[4] + sm->red[5] + sm->red[6] + sm->red[7];
    if (tid < n) sm->sc[tid] = ev;
    __syncthreads();
    float4 acc[4];
    #pragma unroll
    for (int m = 0; m < 4; ++m) acc[m] = {0.f, 0.f, 0.f, 0.f};
    for (int i = wave; i < n; i += 4) {
        float a = sm->sc[i];
        const float* hr = hist + ((size_t)(r0 + i) * BB + b) * UU;
        #pragma unroll
        for (int m = 0; m < 4; ++m) {
            float4 hv = *(const float4*)&hr[m * 256 + lane * 4];
            acc[m].x += a * hv.x; acc[m].y += a * hv.y;
            acc[m].z += a * hv.z; acc[m].w += a * hv.w;
        }
    }
    #pragma unroll
    for (int m = 0; m < 4; ++m)
        *(float4*)&sm->pct[wave][m * 256 + lane * 4] = acc[m];
    __syncthreads();
    int u0 = tid * 4;
    float4 c = {0.f, 0.f, 0.f, 0.f};
    #pragma unroll
    for (int w = 0; w < 4; ++w) {
        float4 pv = *(const float4*)&sm->pct[w][u0];
        c.x += pv.x; c.y += pv.y; c.z += pv.z; c.w += pv.w;
    }
    *(float4*)&attC[(size_t)b * UU + u0] = c;
    if (tid == 0) { attML[b * 2] = mx; attML[b * 2 + 1] = l; }
}

// ---------------------------------------------------------------------------
// One stage S_t = { att(t), g(t), p(t-1), e(t-2) } — mutually independent.
// Blocks: [0,64) att (b,half) | [64,832) GEMM: cell = (blk-64)>>8, jt low 8.
// ---------------------------------------------------------------------------
__global__ __launch_bounds__(256, 4)
void stage_kernel(int t, const float* __restrict__ inputs,
                  float* __restrict__ hist, float* __restrict__ P,
                  float* __restrict__ xg,
                  const float* __restrict__ qall, float* __restrict__ out,
                  const float* __restrict__ packG, const float* __restrict__ packP,
                  const float* __restrict__ packE,
                  const float* __restrict__ gbih, const float* __restrict__ gbhh,
                  const float* __restrict__ pbih, const float* __restrict__ pbhh,
                  const float* __restrict__ ebih, const float* __restrict__ ebhh,
                  float* __restrict__ attC, float* __restrict__ attML) {
    __shared__ SmU sm;
    int blk = blockIdx.x;
    int tid = threadIdx.x;
    if (blk < 64) {
        if (t < TT) {
            int b = blk >> 1, h = blk & 1;
            int slot = t & 1;
            att_half(&sm.a, b, h, tid, t, hist,
                     qall + (size_t)t * BB * UU,
                     attC + (size_t)(slot * 2 + h) * BB * UU,
                     attML + (size_t)(slot * 2 + h) * BB * 2);
        }
        return;
    }
    int gi = blk - 64;
    int cell = gi >> 8;
    int jt = gi & 255;
    if (cell == 0) {          // g(t)
        if (t < TT)
            gru4<false>(sm.wbuf, tid, jt, packG,
                        xg + (size_t)(t & 1) * BB * UU,
                        nullptr, 0.f, nullptr, 0.f, nullptr,
                        hist + (size_t)t * BB * UU, UU,
                        gbih, gbhh,
                        hist + (size_t)(t + 1) * BB * UU, UU,
                        nullptr, nullptr);
    } else if (cell == 1) {   // p(t-1)
        int tp = t - 1;
        if (tp >= 0 && tp < TT) {
            int slot = tp & 1;
            const float* ml1 = attML + (size_t)(slot * 2 + 0) * BB * 2;
            const float* ml2 = attML + (size_t)(slot * 2 + 1) * BB * 2;
            int b = tid >> 3;
            float m1 = ml1[b * 2], l1 = ml1[b * 2 + 1];
            float m2 = ml2[b * 2], l2 = ml2[b * 2 + 1];
            float M = fmaxf(m1, m2);
            float e1 = expf(m1 - M), e2 = expf(m2 - M);
            float denom = e1 * l1 + e2 * l2;
            float a1 = e1 / denom, a2 = e2 / denom;
            int par = tp & 1, pp = (tp >> 1) & 1;
            const float* hP = P + (size_t)(par * 2 + pp) * BB * UU;
            float* oP = P + (size_t)(par * 2 + (1 - pp)) * BB * UU;
            const float* epiU = (tp + 2 < TT) ? inputs + (size_t)(tp + 2) * UU : nullptr;
            float* epiDst = epiU ? xg + (size_t)(tp & 1) * BB * UU : nullptr;
            gru4<true>(sm.wbuf, tid, jt, packP,
                       nullptr,
                       inputs + (size_t)tp * UU,
                       a1, attC + (size_t)(slot * 2 + 0) * BB * UU,
                       a2, attC + (size_t)(slot * 2 + 1) * BB * UU,
                       hP, UU,
                       pbih, pbhh,
                       oP, UU,
                       epiU, epiDst);
        }
    } else {                  // e(t-2)
        int te = t - 2;
        if (te >= 0 && te < TT) {
            int par = te & 1, pp = (te >> 1) & 1;
            const float* xE = P + (size_t)(par * 2 + (1 - pp)) * BB * UU;  // p(te)
            const float* hE = te ? out + (size_t)(te - 1) * UU : nullptr;
            gru4<false>(sm.wbuf, tid, jt, packE,
                        xE, nullptr, 0.f, nullptr, 0.f, nullptr,
                        hE, (size_t)TT * UU,
                        ebih, ebhh,
                        out + (size_t)te * UU, (size_t)TT * UU,
                        nullptr, nullptr);
        }
    }
}

extern "C" void kernel_launch(void* const* d_in, const int* in_sizes, int n_in,
                              void* d_out, int out_size, void* d_ws, size_t ws_size,
                              hipStream_t stream) {
    (void)in_sizes; (void)n_in; (void)out_size; (void)ws_size;
    const float* inputs = (const float*)d_in[0];
    const float* gW   = (const float*)d_in[1];
    const float* gWih = (const float*)d_in[2];
    const float* gWhh = (const float*)d_in[3];
    const float* gbih = (const float*)d_in[4];
    const float* gbhh = (const float*)d_in[5];
    const float* pWih = (const float*)d_in[6];
    const float* pWhh = (const float*)d_in[7];
    const float* pbih = (const float*)d_in[8];
    const float* pbhh = (const float*)d_in[9];
    const float* eWih = (const float*)d_in[10];
    const float* eWhh = (const float*)d_in[11];
    const float* ebih = (const float*)d_in[12];
    const float* ebhh = (const float*)d_in[13];
    float* out = (float*)d_out;

    char* ws = (char*)d_ws;
    size_t off = 0;
    auto alloc = [&](size_t nfloats) {
        float* p = (float*)(ws + off);
        off += nfloats * sizeof(float);
        return p;
    };
    const size_t cellF = (size_t)NJT * NCH * PACKF;   // 6.29 M floats per cell
    float* packG = alloc(cellF);
    float* packP = alloc(cellF);
    float* packE = alloc(cellF);
    float* hist  = alloc((size_t)(TT + 1) * BB * UU);
    float* qall  = alloc((size_t)TT * BB * UU);
    float* P     = alloc((size_t)4 * BB * UU);
    float* xg    = alloc((size_t)2 * BB * UU);
    float* attC  = alloc((size_t)4 * BB * UU);        // [slot][half][b][u]
    float* attML = alloc((size_t)4 * BB * 2);         // [slot][half][b][{m,l}]

    pack_kernel<<<NJT * NCH, 256, 0, stream>>>(gWih, gWhh, packG);
    pack_kernel<<<NJT * NCH, 256, 0, stream>>>(pWih, pWhh, packP);
    pack_kernel<<<NJT * NCH, 256, 0, stream>>>(eWih, eWhh, packE);
    qall_kernel<<<dim3(256, 32), 256, 0, stream>>>(inputs, gW, qall);
    init_kernel<<<128, 256, 0, stream>>>(inputs, hist, P, xg);

    for (int t = 0; t <= TT + 1; ++t) {
        stage_kernel<<<832, 256, 0, stream>>>(t, inputs, hist, P, xg, qall, out,
                                              packG, packP, packE,
                                              gbih, gbhh, pbih, pbhh, ebih, ebhh,
                                              attC, attML);
    }
}

// Round 4
// 6855.948 us; speedup vs baseline: 7.8994x; 7.8994x over previous
//
#include <hip/hip_runtime.h>
#include <math.h>

// Problem constants: U=H=1024, B=32, T=256.
#define UU 1024
#define BB 32
#define TT 256

typedef __attribute__((ext_vector_type(8))) short bf16x8;   // 8 bf16 = 4 VGPRs
typedef __attribute__((ext_vector_type(4))) float f32x4;

// Weight pack geometry (ushort elems). Per cell: [2 planes][sections r,z,nx,nh]
#define WPS   6291456u           // plane stride (elems) = 6M weights
#define WCELL (2u * WPS)
#define SR  0u
#define SZ  2097152u
#define SNX 4194304u
#define SNH 5242880u
// Act pack: per slot [2 planes][64 ks][4 hi][32 b][8 e]
#define APS   65536u
#define ASLOT (2u * APS)
// act-pack element index for (u, b) in x-half; h-half = +32768
#define AEX(u, b) ((((((u) >> 5) * 4 + (((u) >> 3) & 3)) * 32 + (b)) * 8) + ((u) & 7))

__device__ __forceinline__ ushort bf16rne(float v) {
    uint x = __float_as_uint(v);
    uint r = (x + 0x7fffu + ((x >> 16) & 1u)) >> 16;
    return (ushort)r;
}
__device__ __forceinline__ float ubf2f(ushort u) {
    return __uint_as_float(((uint)u) << 16);
}
__device__ __forceinline__ void split2(float v, ushort& h, ushort& l) {
    h = bf16rne(v);
    l = bf16rne(v - ubf2f(h));
}

// ---------------------------------------------------------------------------
// Weight pack (one cell per launch): Wih/Whh (3U x U) -> MFMA A-frag layout.
// Sections: r,z: K=2048 (x||h), 64 jt x 64 ks; nx,nh: K=1024, 64 jt x 32 ks.
// Frag elem idx: sec + (((jt*nks + ks)*4 + hi)*16 + ul)*8 + e
//   maps to W[u = jt*16+ul][k = ks*32 + hi*8 + e].
// ---------------------------------------------------------------------------
__global__ void packw_kernel(const float* __restrict__ Wih,
                             const float* __restrict__ Whh,
                             ushort* __restrict__ wp) {
    int tile = blockIdx.x;  // 12288 tiles
    int sec, jt, ks, nks;
    size_t soff;
    if (tile < 8192) {
        sec = tile >> 12; int l = tile & 4095; jt = l >> 6; ks = l & 63; nks = 64;
        soff = sec ? SZ : SR;
    } else {
        int l2 = tile - 8192; sec = 2 + (l2 >> 11); int l = l2 & 2047; jt = l >> 5; ks = l & 31; nks = 32;
        soff = (sec == 2) ? SNX : SNH;
    }
    int p = threadIdx.x;
    int e0 = (p & 3) * 2, ul = (p >> 2) & 15, hi = p >> 6;
    int u = jt * 16 + ul;
    int kk = ks * 32 + hi * 8 + e0;
    float2 w;
    if (sec < 2) {
        int row = (sec ? 1024 : 0) + u;
        if (kk < 1024) w = *(const float2*)&Wih[(size_t)row * UU + kk];
        else           w = *(const float2*)&Whh[(size_t)row * UU + kk - 1024];
    } else if (sec == 2) {
        w = *(const float2*)&Wih[(size_t)(2048 + u) * UU + kk];
    } else {
        w = *(const float2*)&Whh[(size_t)(2048 + u) * UU + kk];
    }
    ushort h0, l0, h1, l1;
    split2(w.x, h0, l0); split2(w.y, h1, l1);
    size_t ob = soff + ((((size_t)jt * nks + ks) * 4 + hi) * 16 + ul) * 8 + e0;
    *(uint*)(wp + ob)       = (uint)h0 | ((uint)h1 << 16);
    *(uint*)(wp + WPS + ob) = (uint)l0 | ((uint)l1 << 16);
}

// ---------------------------------------------------------------------------
// q_all[t][b][u] = sum_k inputs[b][t][k] * global_W[k][u]  (fp32, round-2)
// ---------------------------------------------------------------------------
__global__ void qall_kernel(const float* __restrict__ x,
                            const float* __restrict__ gW,
                            float* __restrict__ q) {
    __shared__ float xs[32][65];
    int r0 = blockIdx.x * 32, u0 = blockIdx.y * 32;
    int tid = threadIdx.x;
    int rr = tid >> 3, ju = tid & 7;
    float4 acc = {0.f, 0.f, 0.f, 0.f};
    for (int k0 = 0; k0 < UU; k0 += 64) {
        for (int e = tid; e < 32 * 64; e += 256) {
            int lr = e >> 6, lk = e & 63;
            int r = r0 + lr;
            int tt = r >> 5, bb = r & 31;
            xs[lr][lk] = x[((size_t)bb * TT + tt) * UU + k0 + lk];
        }
        __syncthreads();
        #pragma unroll 4
        for (int kk = 0; kk < 64; ++kk) {
            float4 gv = *(const float4*)&gW[(size_t)(k0 + kk) * UU + u0 + ju * 4];
            float xv = xs[rr][kk];
            acc.x += xv * gv.x; acc.y += xv * gv.y;
            acc.z += xv * gv.z; acc.w += xv * gv.w;
        }
        __syncthreads();
    }
    *(float4*)&q[(size_t)(r0 + rr) * UU + u0 + ju * 4] = acc;
}

// ---------------------------------------------------------------------------
// Init: zero hist row0, Pf slots 0,1, h-halves (gpack0, ppack0/1, epack0);
// gpack x-half slots 0,1 = split(u_0), split(u_1). Blocks >=128: bias pack.
// ---------------------------------------------------------------------------
__global__ void init_kernel(const float* __restrict__ inputs,
                            const float* __restrict__ gbih, const float* __restrict__ gbhh,
                            const float* __restrict__ pbih, const float* __restrict__ pbhh,
                            const float* __restrict__ ebih, const float* __restrict__ ebhh,
                            float* __restrict__ hist, float* __restrict__ Pf,
                            ushort* __restrict__ gpack, ushort* __restrict__ ppack,
                            ushort* __restrict__ epack, float* __restrict__ biasp) {
    if (blockIdx.x < 128) {
        int i = blockIdx.x * 256 + threadIdx.x;   // 0..32767
        int b = i >> 10, u = i & 1023;
        hist[i] = 0.f;
        Pf[i] = 0.f; Pf[32768 + i] = 0.f;
        int ex = AEX(u, b);
        int eh = ex + 32768;
        gpack[eh] = 0; gpack[APS + eh] = 0;
        ppack[eh] = 0; ppack[APS + eh] = 0;
        ppack[ASLOT + eh] = 0; ppack[ASLOT + APS + eh] = 0;
        epack[eh] = 0; epack[APS + eh] = 0;
        float x0 = inputs[((size_t)b * TT + 0) * UU + u];
        float x1 = inputs[((size_t)b * TT + 1) * UU + u];
        ushort h, l;
        split2(x0, h, l); gpack[ex] = h; gpack[APS + ex] = l;
        split2(x1, h, l); gpack[ASLOT + ex] = h; gpack[ASLOT + APS + ex] = l;
    } else {
        int idx = (blockIdx.x - 128) * 256 + threadIdx.x;   // 0..12287
        int cell = idx >> 12, g4 = (idx >> 10) & 3, u = idx & 1023;
        const float* bih = (cell == 0) ? gbih : (cell == 1) ? pbih : ebih;
        const float* bhh = (cell == 0) ? gbhh : (cell == 1) ? pbhh : ebhh;
        float v;
        if (g4 == 0) v = bih[u] + bhh[u];
        else if (g4 == 1) v = bih[1024 + u] + bhh[1024 + u];
        else if (g4 == 2) v = bih[2048 + u];
        else v = bhh[2048 + u];
        biasp[idx] = v;
    }
}

// ---------------------------------------------------------------------------
// Stage S_t = { g(t), p(t-1), e(t-2), att(t) } — mutually independent.
// Blocks [0,192): GEMM: cell = blk>>6 (0=g,1=p,2=e), jt = blk&63.
//   8 waves: bt = wave&1 (b-tile), kq = wave>>1 (K quarter of 2048).
//   3 bf16 MFMAs per product pair (hi*hi, hi*lo, lo*hi), fp32 acc.
// Blocks [192,224): attention for batch b = blk-192.
// ---------------------------------------------------------------------------
__global__ __launch_bounds__(512, 1)
void stage_kernel(int t,
                  const float* __restrict__ inputs,
                  const ushort* __restrict__ wpack,
                  const float* __restrict__ biasp,
                  ushort* __restrict__ gpack, ushort* __restrict__ ppack,
                  ushort* __restrict__ epack,
                  float* __restrict__ hist, float* __restrict__ Pf,
                  const float* __restrict__ qall,
                  float* __restrict__ out) {
    __shared__ union {
        float g[2][4][64][12];
        struct { float sc[TT]; float red[16]; float pct[8][UU]; } a;
    } sm;
    const int blk = blockIdx.x, tid = threadIdx.x;
    if (blk < 192) {
        const int cell = blk >> 6, jt = blk & 63;
        const int tc = t - cell;
        if (tc < 0 || tc >= TT) return;
        const int wave = tid >> 6, lane = tid & 63;
        const int bt = wave & 1, kq = wave >> 1;
        const int l15 = lane & 15, hi4 = lane >> 4;
        const ushort* wp = wpack + (size_t)cell * WCELL;
        ushort* apk = (cell == 0) ? gpack : (cell == 1) ? ppack : epack;
        const ushort* ap = apk + (size_t)(tc & 3) * ASLOT;
        // B-frags: [ks][hi][b][e], +1024 elems per ks
        const ushort* bH = ap + ((size_t)hi4 * 32 + bt * 16 + l15) * 8;
        const ushort* bL = bH + APS;
        // A-frags r/z: +512 per ks; n: +512 per local ks
        const size_t aRZ = ((size_t)jt * 256 + hi4) * 128 + (size_t)l15 * 8;
        const ushort* rH = wp + SR + aRZ;  const ushort* rL = rH + WPS;
        const ushort* zH = wp + SZ + aRZ;  const ushort* zL = zH + WPS;
        const size_t aN = ((size_t)jt * 128 + hi4) * 128 + (size_t)l15 * 8;
        const ushort* nH = wp + ((kq < 2) ? SNX : SNH) + aN;
        const ushort* nL = nH + WPS;
        f32x4 accR = {0.f, 0.f, 0.f, 0.f};
        f32x4 accZ = {0.f, 0.f, 0.f, 0.f};
        f32x4 accN = {0.f, 0.f, 0.f, 0.f};
        const int ks0 = kq * 16;
        const int nks0 = (kq & 1) * 16;
        #pragma unroll 2
        for (int ksl = 0; ksl < 16; ++ksl) {
            const size_t ks = ks0 + ksl;
            const size_t ksn = nks0 + ksl;
            bf16x8 vbh = *(const bf16x8*)(bH + ks * 1024);
            bf16x8 vbl = *(const bf16x8*)(bL + ks * 1024);
            bf16x8 vrh = *(const bf16x8*)(rH + ks * 512);
            bf16x8 vrl = *(const bf16x8*)(rL + ks * 512);
            bf16x8 vzh = *(const bf16x8*)(zH + ks * 512);
            bf16x8 vzl = *(const bf16x8*)(zL + ks * 512);
            bf16x8 vnh = *(const bf16x8*)(nH + ksn * 512);
            bf16x8 vnl = *(const bf16x8*)(nL + ksn * 512);
            accR = __builtin_amdgcn_mfma_f32_16x16x32_bf16(vrh, vbh, accR, 0, 0, 0);
            accZ = __builtin_amdgcn_mfma_f32_16x16x32_bf16(vzh, vbh, accZ, 0, 0, 0);
            accN = __builtin_amdgcn_mfma_f32_16x16x32_bf16(vnh, vbh, accN, 0, 0, 0);
            accR = __builtin_amdgcn_mfma_f32_16x16x32_bf16(vrh, vbl, accR, 0, 0, 0);
            accZ = __builtin_amdgcn_mfma_f32_16x16x32_bf16(vzh, vbl, accZ, 0, 0, 0);
            accN = __builtin_amdgcn_mfma_f32_16x16x32_bf16(vnh, vbl, accN, 0, 0, 0);
            accR = __builtin_amdgcn_mfma_f32_16x16x32_bf16(vrl, vbh, accR, 0, 0, 0);
            accZ = __builtin_amdgcn_mfma_f32_16x16x32_bf16(vzl, vbh, accZ, 0, 0, 0);
            accN = __builtin_amdgcn_mfma_f32_16x16x32_bf16(vnl, vbh, accN, 0, 0, 0);
        }
        #pragma unroll
        for (int i = 0; i < 4; ++i) {
            sm.g[bt][kq][lane][i] = accR[i];
            sm.g[bt][kq][lane][4 + i] = accZ[i];
            sm.g[bt][kq][lane][8 + i] = accN[i];
        }
        __syncthreads();
        if (kq != 3) return;
        // epilogue: lane holds units u0..u0+3 for batch b
        const int b = bt * 16 + l15;
        const int u0 = jt * 16 + hi4 * 4;
        float R[4], Z[4], iN[4], hN[4];
        #pragma unroll
        for (int i = 0; i < 4; ++i) {
            R[i] = sm.g[bt][0][lane][i] + sm.g[bt][1][lane][i]
                 + sm.g[bt][2][lane][i] + sm.g[bt][3][lane][i];
            Z[i] = sm.g[bt][0][lane][4 + i] + sm.g[bt][1][lane][4 + i]
                 + sm.g[bt][2][lane][4 + i] + sm.g[bt][3][lane][4 + i];
            iN[i] = sm.g[bt][0][lane][8 + i] + sm.g[bt][1][lane][8 + i];
            hN[i] = sm.g[bt][2][lane][8 + i] + sm.g[bt][3][lane][8 + i];
        }
        const float* bc = biasp + cell * 4096;
        float4 br  = *(const float4*)&bc[u0];
        float4 bz  = *(const float4*)&bc[1024 + u0];
        float4 bni = *(const float4*)&bc[2048 + u0];
        float4 bnh = *(const float4*)&bc[3072 + u0];
        float4 hp = {0.f, 0.f, 0.f, 0.f};
        if (cell == 0)      hp = *(const float4*)&hist[((size_t)tc * BB + b) * UU + u0];
        else if (cell == 1) hp = *(const float4*)&Pf[(size_t)(tc & 3) * BB * UU + (size_t)b * UU + u0];
        else if (tc > 0)    hp = *(const float4*)&out[((size_t)b * TT + tc - 1) * UU + u0];
        float val[4];
        #pragma unroll
        for (int i = 0; i < 4; ++i) {
            float r = 1.f / (1.f + expf(-(R[i] + (&br.x)[i])));
            float z = 1.f / (1.f + expf(-(Z[i] + (&bz.x)[i])));
            float n = tanhf(iN[i] + (&bni.x)[i] + r * (hN[i] + (&bnh.x)[i]));
            val[i] = (1.f - z) * n + z * (&hp.x)[i];
        }
        ushort4 vh, vl;
        #pragma unroll
        for (int i = 0; i < 4; ++i) split2(val[i], (&vh.x)[i], (&vl.x)[i]);
        const int ex = AEX(u0, b);
        float4 fv = {val[0], val[1], val[2], val[3]};
        if (cell == 0) {        // g(t): hist[t+1] fp32 + gpack_h[(t+1)&3]
            *(float4*)&hist[((size_t)(tc + 1) * BB + b) * UU + u0] = fv;
            ushort* d = gpack + (size_t)((tc + 1) & 3) * ASLOT;
            *(ushort4*)(d + ex + 32768) = vh;
            *(ushort4*)(d + APS + ex + 32768) = vl;
        } else if (cell == 1) { // p(tp)
            const int tp = tc;
            ushort* d = epack + (size_t)(tp & 3) * ASLOT;      // e(tp) x-operand
            *(ushort4*)(d + ex) = vh;
            *(ushort4*)(d + APS + ex) = vl;
            if (tp + 2 < TT) {
                *(float4*)&Pf[(size_t)((tp + 2) & 3) * BB * UU + (size_t)b * UU + u0] = fv;
                ushort* d2 = ppack + (size_t)((tp + 2) & 3) * ASLOT;   // p(tp+2) h-operand
                *(ushort4*)(d2 + ex + 32768) = vh;
                *(ushort4*)(d2 + APS + ex + 32768) = vl;
                float4 uv = *(const float4*)&inputs[((size_t)b * TT + tp + 2) * UU + u0];
                ushort4 gh, gl;
                #pragma unroll
                for (int i = 0; i < 4; ++i) split2(val[i] + (&uv.x)[i], (&gh.x)[i], (&gl.x)[i]);
                ushort* d3 = gpack + (size_t)((tp + 2) & 3) * ASLOT;   // g(tp+2) x-operand
                *(ushort4*)(d3 + ex) = gh;
                *(ushort4*)(d3 + APS + ex) = gl;
            }
        } else {                // e(te): out fp32 + epack_h[(te+1)&3]
            const int te = tc;
            *(float4*)&out[((size_t)b * TT + te) * UU + u0] = fv;
            if (te + 1 < TT) {
                ushort* d = epack + (size_t)((te + 1) & 3) * ASLOT;
                *(ushort4*)(d + ex + 32768) = vh;
                *(ushort4*)(d + APS + ex + 32768) = vl;
            }
        }
    } else {
        // ---------------- attention for batch b ----------------
        if (t >= TT) return;
        const int b = blk - 192;
        const int nt = t + 1;
        const int wave = tid >> 6, lane = tid & 63;
        const float* qb = qall + ((size_t)t * BB + b) * UU;
        float4 qr[4];
        #pragma unroll
        for (int m = 0; m < 4; ++m) qr[m] = *(const float4*)&qb[m * 256 + lane * 4];
        for (int tp = wave; tp < nt; tp += 8) {
            const float* hr = hist + ((size_t)tp * BB + b) * UU;
            float s = 0.f;
            #pragma unroll
            for (int m = 0; m < 4; ++m) {
                float4 hv = *(const float4*)&hr[m * 256 + lane * 4];
                s += hv.x * qr[m].x + hv.y * qr[m].y + hv.z * qr[m].z + hv.w * qr[m].w;
            }
            #pragma unroll
            for (int off = 32; off; off >>= 1) s += __shfl_xor(s, off);
            if (lane == 0) sm.a.sc[tp] = s;
        }
        __syncthreads();
        float v = (tid < nt) ? sm.a.sc[tid] : -INFINITY;
        float mx = v;
        #pragma unroll
        for (int off = 32; off; off >>= 1) mx = fmaxf(mx, __shfl_xor(mx, off));
        if (lane == 0) sm.a.red[wave] = mx;
        __syncthreads();
        mx = sm.a.red[0];
        #pragma unroll
        for (int w = 1; w < 8; ++w) mx = fmaxf(mx, sm.a.red[w]);
        float ev = (tid < nt) ? expf(v - mx) : 0.f;
        float s2 = ev;
        #pragma unroll
        for (int off = 32; off; off >>= 1) s2 += __shfl_xor(s2, off);
        if (lane == 0) sm.a.red[8 + wave] = s2;
        __syncthreads();
        float l = 0.f;
        #pragma unroll
        for (int w = 0; w < 8; ++w) l += sm.a.red[8 + w];
        float inv = 1.f / l;
        if (tid < nt) sm.a.sc[tid] = ev * inv;
        __syncthreads();
        float4 acc[4];
        #pragma unroll
        for (int m = 0; m < 4; ++m) acc[m] = {0.f, 0.f, 0.f, 0.f};
        for (int i = wave; i < nt; i += 8) {
            float a = sm.a.sc[i];
            const float* hr = hist + ((size_t)i * BB + b) * UU;
            #pragma unroll
            for (int m = 0; m < 4; ++m) {
                float4 hv = *(const float4*)&hr[m * 256 + lane * 4];
                acc[m].x += a * hv.x; acc[m].y += a * hv.y;
                acc[m].z += a * hv.z; acc[m].w += a * hv.w;
            }
        }
        #pragma unroll
        for (int m = 0; m < 4; ++m)
            *(float4*)&sm.a.pct[wave][m * 256 + lane * 4] = acc[m];
        __syncthreads();
        // final: xp = u_t + ctx -> ppack_x[t&3] (p(t)'s x-operand), 2 u per thread
        const int u2 = tid * 2;
        float cx = 0.f, cy = 0.f;
        #pragma unroll
        for (int w = 0; w < 8; ++w) {
            float2 pv = *(const float2*)&sm.a.pct[w][u2];
            cx += pv.x; cy += pv.y;
        }
        float2 uv = *(const float2*)&inputs[((size_t)b * TT + t) * UU + u2];
        float v0 = cx + uv.x, v1 = cy + uv.y;
        ushort h0, l0, h1, l1;
        split2(v0, h0, l0); split2(v1, h1, l1);
        ushort* d = ppack + (size_t)(t & 3) * ASLOT;
        const int ix = AEX(u2, b);
        *(uint*)(d + ix) = (uint)h0 | ((uint)h1 << 16);
        *(uint*)(d + APS + ix) = (uint)l0 | ((uint)l1 << 16);
    }
}

extern "C" void kernel_launch(void* const* d_in, const int* in_sizes, int n_in,
                              void* d_out, int out_size, void* d_ws, size_t ws_size,
                              hipStream_t stream) {
    (void)in_sizes; (void)n_in; (void)out_size; (void)ws_size;
    const float* inputs = (const float*)d_in[0];
    const float* gW   = (const float*)d_in[1];
    const float* gWih = (const float*)d_in[2];
    const float* gWhh = (const float*)d_in[3];
    const float* gbih = (const float*)d_in[4];
    const float* gbhh = (const float*)d_in[5];
    const float* pWih = (const float*)d_in[6];
    const float* pWhh = (const float*)d_in[7];
    const float* pbih = (const float*)d_in[8];
    const float* pbhh = (const float*)d_in[9];
    const float* eWih = (const float*)d_in[10];
    const float* eWhh = (const float*)d_in[11];
    const float* ebih = (const float*)d_in[12];
    const float* ebhh = (const float*)d_in[13];
    float* out = (float*)d_out;

    char* ws = (char*)d_ws;
    size_t off = 0;
    auto alloc = [&](size_t bytes) {
        void* p = ws + off;
        off += (bytes + 255) & ~(size_t)255;
        return p;
    };
    ushort* wpack = (ushort*)alloc((size_t)3 * WCELL * 2);       // 75.5 MB
    ushort* gpack = (ushort*)alloc((size_t)4 * ASLOT * 2);       // 1 MB
    ushort* ppack = (ushort*)alloc((size_t)4 * ASLOT * 2);
    ushort* epack = (ushort*)alloc((size_t)4 * ASLOT * 2);
    float* hist  = (float*)alloc((size_t)(TT + 1) * BB * UU * 4);  // 33.7 MB
    float* qall  = (float*)alloc((size_t)TT * BB * UU * 4);        // 33.5 MB
    float* Pf    = (float*)alloc((size_t)4 * BB * UU * 4);
    float* biasp = (float*)alloc((size_t)3 * 4096 * 4);

    packw_kernel<<<12288, 256, 0, stream>>>(gWih, gWhh, wpack);
    packw_kernel<<<12288, 256, 0, stream>>>(pWih, pWhh, wpack + WCELL);
    packw_kernel<<<12288, 256, 0, stream>>>(eWih, eWhh, wpack + 2 * (size_t)WCELL);
    qall_kernel<<<dim3(256, 32), 256, 0, stream>>>(inputs, gW, qall);
    init_kernel<<<176, 256, 0, stream>>>(inputs, gbih, gbhh, pbih, pbhh, ebih, ebhh,
                                         hist, Pf, gpack, ppack, epack, biasp);

    for (int t = 0; t <= TT + 1; ++t) {
        stage_kernel<<<224, 512, 0, stream>>>(t, inputs, wpack, biasp,
                                              gpack, ppack, epack,
                                              hist, Pf, qall, out);
    }
}